// Round 24
// baseline (185.510 us; speedup 1.0000x reference)
//
#include <hip/hip_runtime.h>
#include <hip/hip_fp16.h>
#include <cstdint>
#include <cstddef>

typedef _Float16 f16;
typedef _Float16 f16x8 __attribute__((ext_vector_type(8)));
typedef _Float16 f16x4 __attribute__((ext_vector_type(4)));
typedef float    f32x4 __attribute__((ext_vector_type(4)));

#define MFMA(a, b, c) __builtin_amdgcn_mfma_f32_16x16x32_f16(a, b, c, 0, 0, 0)

// B=4, S=2048, D=1024, H=16, KS=VS=64, O=1024.

__device__ __forceinline__ void gload_lds16(const f16* g, f16* l) {
    __builtin_amdgcn_global_load_lds(
        (const __attribute__((address_space(1))) void*)g,
        (__attribute__((address_space(3))) void*)l, 16, 0, 0);
}

// ---------------- weight transpose + convert to fp16 (all 4 fused) ----------
__global__ void k_transpose_all(const float* __restrict__ Wq, const float* __restrict__ Wk,
                                const float* __restrict__ Wv, const float* __restrict__ Wo,
                                f16* __restrict__ WT, f16* __restrict__ WoT) {
    __shared__ float T[64][65];
    const int bx = blockIdx.x;
    const int widx = bx >> 8, sub = bx & 255;
    const int nb = sub >> 4, db = sub & 15;
    const int tid = threadIdx.x;
    const float* W = widx == 0 ? Wq : (widx == 1 ? Wk : (widx == 2 ? Wv : Wo));
    f16* Wt = (widx < 3) ? (WT + (size_t)widx * 1048576) : WoT;
    const float* src = (widx < 3) ? (W + nb * 65536 + db * 4096)
                                  : (W + db * 65536 + nb * 64);
    const int rstride = (widx < 3) ? 64 : 1024;
    {
        int nn = tid & 63, d0 = tid >> 6;
#pragma unroll
        for (int p = 0; p < 16; ++p) {
            int dd = p * 4 + d0;
            T[dd][nn] = src[dd * rstride + nn];
        }
    }
    __syncthreads();
    {
        int dd = tid & 63, n0 = tid >> 6;
#pragma unroll
        for (int p = 0; p < 16; ++p) {
            int nn = p * 4 + n0;
            Wt[(size_t)(nb * 64 + nn) * 1024 + db * 64 + dd] = (f16)T[dd][nn];
        }
    }
}

// ---------------------- 256x128-tile GEMM building blocks --------------------
// LDS chunk layout (16B chunks): chunk(row, cc) = (row>>3)*68 + (row&7)*8 + cc
#define G256_STAGE(AD, BD, ASRC, BSRC, KT)                                      \
    do {                                                                        \
        int ktc = (KT);                                                         \
        _Pragma("unroll")                                                       \
        for (int i2 = 0; i2 < 4; ++i2) {                                        \
            int gA = wid * 4 + i2;                                              \
            gload_lds16(&(ASRC)[(size_t)(row0 + gA * 8 + (lane >> 3)) * 1024    \
                                + ktc * 64 + (lane & 7) * 8],                   \
                        &(AD)[(gA * 68 + lane) * 8]);                           \
        }                                                                       \
        _Pragma("unroll")                                                       \
        for (int i2 = 0; i2 < 2; ++i2) {                                        \
            int gB = wid * 2 + i2;                                              \
            gload_lds16(&(BSRC)[(size_t)(col0 + gB * 8 + (lane >> 3)) * 1024    \
                                + ktc * 64 + (lane & 7) * 8],                   \
                        &(BD)[(gB * 68 + lane) * 8]);                           \
        }                                                                       \
    } while (0)

#define G256_STAGE_B(BD, BSRC, KT)                                             \
    do {                                                                        \
        int ktc = (KT);                                                         \
        _Pragma("unroll")                                                       \
        for (int i2 = 0; i2 < 2; ++i2) {                                        \
            int gB = wid * 2 + i2;                                              \
            gload_lds16(&(BSRC)[(size_t)(col0 + gB * 8 + (lane >> 3)) * 1024    \
                                + ktc * 64 + (lane & 7) * 8],                   \
                        &(BD)[(gB * 68 + lane) * 8]);                           \
        }                                                                       \
    } while (0)

// A-side fused f32->f16 staging, DOUBLE-BUFFERED registers (r23 lesson:
// single-buffered A-regs force vmcnt(0) drains — the m218 anti-pattern).
#define QKV_ISSUE_A(ALO, AHI, KT)                                               \
    do {                                                                        \
        int ktc = (KT);                                                         \
        _Pragma("unroll")                                                       \
        for (int i2 = 0; i2 < 4; ++i2) {                                        \
            int gA = wid * 4 + i2;                                              \
            const float* p = &Af[(size_t)(row0 + gA * 8 + (lane >> 3)) * 1024   \
                                 + ktc * 64 + (lane & 7) * 8];                  \
            ALO[i2] = *(const float4*)p;                                        \
            AHI[i2] = *(const float4*)(p + 4);                                  \
        }                                                                       \
    } while (0)

#define QKV_WRITE_A(AD, ALO, AHI)                                               \
    do {                                                                        \
        _Pragma("unroll")                                                       \
        for (int i2 = 0; i2 < 4; ++i2) {                                        \
            int gA = wid * 4 + i2;                                              \
            union { uint32_t u[4]; f16x8 v; } hh;                               \
            hh.u[0] = __builtin_bit_cast(uint32_t,                              \
                        __builtin_amdgcn_cvt_pkrtz(ALO[i2].x, ALO[i2].y));      \
            hh.u[1] = __builtin_bit_cast(uint32_t,                              \
                        __builtin_amdgcn_cvt_pkrtz(ALO[i2].z, ALO[i2].w));      \
            hh.u[2] = __builtin_bit_cast(uint32_t,                              \
                        __builtin_amdgcn_cvt_pkrtz(AHI[i2].x, AHI[i2].y));      \
            hh.u[3] = __builtin_bit_cast(uint32_t,                              \
                        __builtin_amdgcn_cvt_pkrtz(AHI[i2].z, AHI[i2].w));      \
            *(f16x8*)&(AD)[(gA * 68 + lane) * 8] = hh.v;                        \
        }                                                                       \
    } while (0)

#define G256_COMPUTE(AB, BB)                                                    \
    do {                                                                        \
        _Pragma("unroll")                                                       \
        for (int kk = 0; kk < 2; ++kk) {                                        \
            f16x8 af[4], bf[4];                                                 \
            _Pragma("unroll")                                                   \
            for (int m = 0; m < 4; ++m) {                                       \
                int rw = wm * 64 + m * 16 + lr;                                 \
                af[m] = *(const f16x8*)&(AB)[((rw >> 3) * 68 + (rw & 7) * 8     \
                                              + kk * 4 + lg) * 8];              \
            }                                                                   \
            _Pragma("unroll")                                                   \
            for (int n = 0; n < 4; ++n) {                                       \
                int rw = wn * 64 + n * 16 + lr;                                 \
                bf[n] = *(const f16x8*)&(BB)[((rw >> 3) * 68 + (rw & 7) * 8     \
                                              + kk * 4 + lg) * 8];              \
            }                                                                   \
            _Pragma("unroll")                                                   \
            for (int m = 0; m < 4; ++m)                                         \
                _Pragma("unroll")                                               \
                for (int n = 0; n < 4; ++n)                                     \
                    acc[m][n] = MFMA(af[m], bf[n], acc[m][n]);                  \
        }                                                                       \
    } while (0)

#define G256_PIPELINE(ASRC, BSRC)                                              \
    int cur = 0, nx1 = 1, nx2 = 2;                                             \
    G256_STAGE(As3, Bs3, ASRC, BSRC, 0);                                       \
    for (int t = 0; t < 16; ++t) {                                             \
        int tn = t < 15 ? t + 1 : 15;                                          \
        G256_STAGE(As3 + nx1 * 17408, Bs3 + nx1 * 8704, ASRC, BSRC, tn);       \
        asm volatile("s_waitcnt vmcnt(6)" ::: "memory");                       \
        __builtin_amdgcn_sched_barrier(0);                                     \
        __builtin_amdgcn_s_barrier();                                          \
        __builtin_amdgcn_sched_barrier(0);                                     \
        const f16* Ab = As3 + cur * 17408;                                     \
        const f16* Bb = Bs3 + cur * 8704;                                      \
        G256_COMPUTE(Ab, Bb);                                                  \
        int tmp = cur; cur = nx1; nx1 = nx2; nx2 = tmp;                        \
    }

// --------------------------- fused q/k/v GEMM (256x128, f32 A) ---------------
// Counted-vmcnt fused pipeline: body(t) = stage B(t+1) + issue A(t+1) into the
// OTHER regset [10 VM ops] -> vmcnt(10) [waits A(t)/B(t) only; the 10 stay in
// flight across barrier+compute] -> ds_write A(t) -> lgkmcnt(0) -> barrier ->
// compute(t). 3-buffer LDS rotation: every write >=1 barrier from its readers.
// Only tile 15 drains. A-regsets alternate by parity (static names, rule #20).
__global__ __launch_bounds__(512, 1) void k_gemm_qkv256(
    const float* __restrict__ Qf, const float* __restrict__ Kf, const float* __restrict__ Vf,
    const f16* __restrict__ WT, const float* __restrict__ bq,
    const float* __restrict__ bk, const float* __restrict__ bv,
    f16* __restrict__ qout, f16* __restrict__ kout, f16* __restrict__ vout, float SC) {
    __shared__ f16 As3[3 * 17408];
    __shared__ f16 Bs3[3 * 8704];
    const int yy = blockIdx.y;
    const int seg = yy >> 3;
    const float* Af = seg == 0 ? Qf : (seg == 1 ? Kf : Vf);
    const f16* Bt   = WT + (size_t)seg * 1048576;
    const float* bias = seg == 0 ? bq : (seg == 1 ? bk : bv);
    const float scale = seg == 0 ? SC : 1.0f;

    const int tid = threadIdx.x;
    const int wid = tid >> 6, lane = tid & 63;
    const int wm = wid >> 1, wn = wid & 1;
    const int lr = lane & 15, lg = lane >> 4;
    const int row0 = blockIdx.x * 256, col0 = (yy & 7) * 128;

    f32x4 acc[4][4];
#pragma unroll
    for (int m = 0; m < 4; ++m)
#pragma unroll
        for (int n = 0; n < 4; ++n) acc[m][n] = (f32x4){0.f, 0.f, 0.f, 0.f};

    float4 aloA[4], ahiA[4], aloB[4], ahiB[4];

    // prologue: tile 0 -> regset A + B-stage buf 0
    G256_STAGE_B(Bs3, Bt, 0);
    QKV_ISSUE_A(aloA, ahiA, 0);

    int cur = 0, nx1 = 1, nx2 = 2;
    for (int tp = 0; tp < 8; ++tp) {
        const int t0 = 2 * tp;
        // ---- even tile t0 (A in regset A) ----
        {
            G256_STAGE_B(Bs3 + nx1 * 8704, Bt, t0 + 1);
            QKV_ISSUE_A(aloB, ahiB, t0 + 1);
            asm volatile("s_waitcnt vmcnt(10)" ::: "memory");
            __builtin_amdgcn_sched_barrier(0);
            QKV_WRITE_A(As3 + cur * 17408, aloA, ahiA);
            asm volatile("s_waitcnt lgkmcnt(0)" ::: "memory");
            __builtin_amdgcn_sched_barrier(0);
            __builtin_amdgcn_s_barrier();
            __builtin_amdgcn_sched_barrier(0);
            G256_COMPUTE(As3 + cur * 17408, Bs3 + cur * 8704);
            int tmp = cur; cur = nx1; nx1 = nx2; nx2 = tmp;
        }
        // ---- odd tile t0+1 (A in regset B) ----
        {
            const int t1 = t0 + 1;
            if (t1 < 15) {
                G256_STAGE_B(Bs3 + nx1 * 8704, Bt, t1 + 1);
                QKV_ISSUE_A(aloA, ahiA, t1 + 1);
                asm volatile("s_waitcnt vmcnt(10)" ::: "memory");
            } else {
                asm volatile("s_waitcnt vmcnt(0)" ::: "memory");
            }
            __builtin_amdgcn_sched_barrier(0);
            QKV_WRITE_A(As3 + cur * 17408, aloB, ahiB);
            asm volatile("s_waitcnt lgkmcnt(0)" ::: "memory");
            __builtin_amdgcn_sched_barrier(0);
            __builtin_amdgcn_s_barrier();
            __builtin_amdgcn_sched_barrier(0);
            G256_COMPUTE(As3 + cur * 17408, Bs3 + cur * 8704);
            int tmp = cur; cur = nx1; nx1 = nx2; nx2 = tmp;
        }
    }

#pragma unroll
    for (int m = 0; m < 4; ++m) {
#pragma unroll
        for (int n = 0; n < 4; ++n) {
            int col = col0 + wn * 64 + n * 16 + lr;
            float bv_ = bias[col];
            int rowb = row0 + wm * 64 + m * 16 + lg * 4;
            int srow = rowb & 2047;
            if (seg == 0) {
#pragma unroll
                for (int r = 0; r < 4; ++r) {
                    int row = rowb + r;
                    size_t a = ((size_t)((row >> 11) * 16 + (col >> 6)) * 2048 + (row & 2047)) * 64 + (col & 63);
                    qout[a] = (f16)((acc[m][n][r] + bv_) * scale);
                }
            } else if (seg == 1) {
                int ks5 = srow & 31;
                int p0 = ((ks5 >> 2) & 1) * 16 + (ks5 >> 3) * 4 + (ks5 & 3);
                size_t abase = (size_t)((rowb >> 11) * 16 + (col >> 6)) * 131072
                             + (size_t)(srow >> 5) * 2048
                             + (size_t)(p0 >> 4) * 512
                             + (size_t)((col & 63) >> 5) * 1024
                             + (size_t)((col & 31) >> 3) * 128
                             + (col & 7);
#pragma unroll
                for (int r = 0; r < 4; ++r)
                    kout[abase + (size_t)((p0 & 15) + r) * 8] = (f16)(acc[m][n][r] + bv_);
            } else {
                size_t a = (size_t)((rowb >> 11) * 16 + (col >> 6)) * 131072
                         + (size_t)(srow >> 5) * 2048
                         + (size_t)((col & 63) >> 4) * 512
                         + (size_t)((srow & 31) >> 3) * 128
                         + (size_t)(col & 15) * 8
                         + (srow & 7);
                f16x4 ov;
#pragma unroll
                for (int r = 0; r < 4; ++r) ov[r] = (f16)(acc[m][n][r] + bv_);
                *(f16x4*)&vout[a] = ov;
            }
        }
    }
}

// ------------------------------ output GEMM (256x128) ------------------------
__global__ __launch_bounds__(512, 1) void k_gemm_out256(const f16* __restrict__ A,
                                                        const f16* __restrict__ Bt,
                                                        const float* __restrict__ bias,
                                                        float* __restrict__ Cout) {
    __shared__ f16 As3[3 * 17408];
    __shared__ f16 Bs3[3 * 8704];
    const int tid = threadIdx.x;
    const int wid = tid >> 6, lane = tid & 63;
    const int wm = wid >> 1, wn = wid & 1;
    const int lr = lane & 15, lg = lane >> 4;
    const int row0 = blockIdx.x * 256, col0 = blockIdx.y * 128;

    f32x4 acc[4][4];
#pragma unroll
    for (int m = 0; m < 4; ++m)
#pragma unroll
        for (int n = 0; n < 4; ++n) acc[m][n] = (f32x4){0.f, 0.f, 0.f, 0.f};

    G256_PIPELINE(A, Bt)

#pragma unroll
    for (int m = 0; m < 4; ++m) {
#pragma unroll
        for (int n = 0; n < 4; ++n) {
            int col = col0 + wn * 64 + n * 16 + lr;
            float bv = bias[col];
#pragma unroll
            for (int r = 0; r < 4; ++r) {
                int row = row0 + wm * 64 + m * 16 + lg * 4 + r;
                Cout[(size_t)row * 1024 + col] = acc[m][n][r] + bv;
            }
        }
    }
}

// ------------------------------ attention (r22 winner, unchanged) ------------
#define ATTN_TILE(Kc, Vc)                                                     \
    do {                                                                      \
        f16x8 ka0 = *(const f16x8*)&(Kc)[fo];                                 \
        f16x8 ka1 = *(const f16x8*)&(Kc)[fo + 1024];                          \
        f16x8 ka2 = *(const f16x8*)&(Kc)[fo + 512];                           \
        f16x8 ka3 = *(const f16x8*)&(Kc)[fo + 1536];                          \
        f32x4 st[2][2];                                                       \
        __builtin_amdgcn_s_setprio(1);                                        \
        _Pragma("unroll")                                                     \
        for (int qt = 0; qt < 2; ++qt) {                                      \
            float nm = -m_r[qt];                                              \
            f32x4 z = (f32x4){nm, nm, nm, nm};                                \
            z = MFMA(ka0, qf[qt][0], z);                                      \
            z = MFMA(ka1, qf[qt][1], z);                                      \
            st[qt][0] = z;                                                    \
            f32x4 z2 = (f32x4){nm, nm, nm, nm};                               \
            z2 = MFMA(ka2, qf[qt][0], z2);                                    \
            z2 = MFMA(ka3, qf[qt][1], z2);                                    \
            st[qt][1] = z2;                                                   \
        }                                                                     \
        __builtin_amdgcn_s_setprio(0);                                        \
        f16x8 vv0 = *(const f16x8*)&(Vc)[fo];                                 \
        f16x8 vv1 = *(const f16x8*)&(Vc)[fo + 512];                           \
        f16x8 vv2 = *(const f16x8*)&(Vc)[fo + 1024];                          \
        f16x8 vv3 = *(const f16x8*)&(Vc)[fo + 1536];                          \
        {                                                                     \
            float lm[2];                                                      \
            _Pragma("unroll")                                                 \
            for (int qt = 0; qt < 2; ++qt) {                                  \
                float a0 = fmaxf(fmaxf(st[qt][0][0], st[qt][0][1]), st[qt][0][2]); \
                float b0 = fmaxf(fmaxf(st[qt][0][3], st[qt][1][0]), st[qt][1][1]); \
                float c0 = fmaxf(fmaxf(st[qt][1][2], st[qt][1][3]), a0);      \
                lm[qt] = fmaxf(b0, c0);                                       \
            }                                                                 \
            if (__any((lm[0] > THR) || (lm[1] > THR))) {                      \
                _Pragma("unroll")                                             \
                for (int qt = 0; qt < 2; ++qt) {                              \
                    float t0v = lm[qt];                                       \
                    t0v = fmaxf(t0v, __shfl_xor(t0v, 16, 64));                \
                    t0v = fmaxf(t0v, __shfl_xor(t0v, 32, 64));                \
                    float delta = fmaxf(0.f, t0v);                            \
                    float alpha = __builtin_amdgcn_exp2f(-delta);             \
                    _Pragma("unroll")                                         \
                    for (int m = 0; m < 4; ++m)                               \
                        _Pragma("unroll")                                     \
                        for (int r = 0; r < 4; ++r) o[qt][m][r] *= alpha;     \
                    _Pragma("unroll")                                         \
                    for (int r = 0; r < 4; ++r) ol[qt][r] *= alpha;           \
                    m_r[qt] += delta;                                         \
                    _Pragma("unroll")                                         \
                    for (int t = 0; t < 2; ++t)                               \
                        _Pragma("unroll")                                     \
                        for (int r = 0; r < 4; ++r) st[qt][t][r] -= delta;    \
                }                                                             \
            }                                                                 \
        }                                                                     \
        f16x8 pf[2];                                                          \
        _Pragma("unroll")                                                     \
        for (int qt = 0; qt < 2; ++qt) {                                      \
            union { uint32_t u[4]; f16x8 v; } bb;                             \
            _Pragma("unroll")                                                 \
            for (int t = 0; t < 2; ++t)                                       \
                _Pragma("unroll")                                             \
                for (int pr = 0; pr < 2; ++pr) {                              \
                    float e0 = __builtin_amdgcn_exp2f(st[qt][t][2 * pr]);     \
                    float e1 = __builtin_amdgcn_exp2f(st[qt][t][2 * pr + 1]); \
                    auto hp = __builtin_amdgcn_cvt_pkrtz(e0, e1);             \
                    bb.u[t * 2 + pr] = __builtin_bit_cast(uint32_t, hp);      \
                }                                                             \
            pf[qt] = bb.v;                                                    \
        }                                                                     \
        __builtin_amdgcn_s_setprio(1);                                        \
        _Pragma("unroll")                                                     \
        for (int qt = 0; qt < 2; ++qt) {                                      \
            o[qt][0] = MFMA(vv0, pf[qt], o[qt][0]);                           \
            o[qt][1] = MFMA(vv1, pf[qt], o[qt][1]);                           \
            o[qt][2] = MFMA(vv2, pf[qt], o[qt][2]);                           \
            o[qt][3] = MFMA(vv3, pf[qt], o[qt][3]);                           \
            ol[qt]   = MFMA(ones, pf[qt], ol[qt]);                            \
        }                                                                     \
        __builtin_amdgcn_s_setprio(0);                                        \
    } while (0)

__global__ __launch_bounds__(512, 4) void k_attn(const f16* __restrict__ q,
                                                 const f16* __restrict__ k2,
                                                 const f16* __restrict__ v2,
                                                 f16* __restrict__ cat) {
    const int g = blockIdx.x;                 // 0..511
    const int xcd = g & 7, i = g >> 3;        // i: 0..63
    const int bh = xcd * 8 + (i >> 3);        // 8 bh per XCD (K/V L2 locality)
    const int qb = i & 7;                     // 8 q-blocks of 256 rows
    const int b = bh >> 4, h = bh & 15;

    const int tid = threadIdx.x, wid = tid >> 6, lane = tid & 63;
    const int lr = lane & 15, lg = lane >> 4;
    const int qw = qb * 256 + wid * 32;       // this wave's 32 q-rows

    __shared__ f16 Ks[4][2048];
    __shared__ f16 Vs[4][2048];

    const float THR = 8.0f;

    f16x8 qf[2][2];
#pragma unroll
    for (int qt = 0; qt < 2; ++qt)
#pragma unroll
        for (int hf = 0; hf < 2; ++hf)
            qf[qt][hf] = *(const f16x8*)&q[((size_t)bh * 2048 + qw + qt * 16 + lr) * 64 + hf * 32 + lg * 8];

    const f16* kt = k2 + (size_t)bh * 131072;
    const f16* vt = v2 + (size_t)bh * 131072;
    const bool sgK = (tid < 256);
    const int so2 = (tid & 255) * 8;
    const int fo = lane * 8;

    f16x8 ones;
#pragma unroll
    for (int j = 0; j < 8; ++j) ones[j] = (f16)1.0f;

    f32x4 o[2][4], ol[2];
#pragma unroll
    for (int qt = 0; qt < 2; ++qt) {
#pragma unroll
        for (int m = 0; m < 4; ++m) o[qt][m] = (f32x4){0.f, 0.f, 0.f, 0.f};
        ol[qt] = (f32x4){0.f, 0.f, 0.f, 0.f};
    }
    float m_r[2] = {0.f, 0.f};

    if (sgK) {
        gload_lds16(kt + so2, &Ks[0][so2]);
        gload_lds16(kt + 2048 + so2, &Ks[1][so2]);
    } else {
        gload_lds16(vt + so2, &Vs[0][so2]);
        gload_lds16(vt + 2048 + so2, &Vs[1][so2]);
    }
    __syncthreads();

    const bool rev = (wid & 1);
    for (int pp = 0; pp < 32; ++pp) {
        const int t0 = 2 * pp;
        const int ba = t0 & 3, bb2 = (t0 + 1) & 3;
        const int bc = (t0 + 2) & 3, bd = (t0 + 3) & 3;

        if (sgK) {
            gload_lds16(kt + (size_t)(t0 + 2) * 2048 + so2, &Ks[bc][so2]);
            gload_lds16(kt + (size_t)(t0 + 3) * 2048 + so2, &Ks[bd][so2]);
        } else {
            gload_lds16(vt + (size_t)(t0 + 2) * 2048 + so2, &Vs[bc][so2]);
            gload_lds16(vt + (size_t)(t0 + 3) * 2048 + so2, &Vs[bd][so2]);
        }

        if (rev) {
            ATTN_TILE(&Ks[bb2][0], &Vs[bb2][0]);
            ATTN_TILE(&Ks[ba][0], &Vs[ba][0]);
        } else {
            ATTN_TILE(&Ks[ba][0], &Vs[ba][0]);
            ATTN_TILE(&Ks[bb2][0], &Vs[bb2][0]);
        }

        __syncthreads();
    }

#pragma unroll
    for (int qt = 0; qt < 2; ++qt) {
        float inv = 1.f / ol[qt][0];
        size_t cb = ((size_t)b * 2048 + qw + qt * 16 + lr) * 1024 + h * 64 + lg * 4;
#pragma unroll
        for (int m = 0; m < 4; ++m) {
            f16x4 ov;
#pragma unroll
            for (int r = 0; r < 4; ++r) ov[r] = (f16)(o[qt][m][r] * inv);
            *(f16x4*)&cat[cb + m * 16] = ov;
        }
    }
}

// ---------------------------------------------------------------------------
extern "C" void kernel_launch(void* const* d_in, const int* in_sizes, int n_in,
                              void* d_out, int out_size, void* d_ws, size_t ws_size,
                              hipStream_t stream) {
    const float* Q  = (const float*)d_in[0];
    const float* K  = (const float*)d_in[1];
    const float* V  = (const float*)d_in[2];
    const float* Wq = (const float*)d_in[3];
    const float* bq = (const float*)d_in[4];
    const float* Wk = (const float*)d_in[5];
    const float* bk = (const float*)d_in[6];
    const float* Wv = (const float*)d_in[7];
    const float* bv = (const float*)d_in[8];
    const float* Wo = (const float*)d_in[9];
    const float* bo = (const float*)d_in[10];

    char* ws = (char*)d_ws;
    size_t off = 0;
    auto alloc = [&](size_t bytes) {
        char* p = ws + off;
        off += (bytes + 255) & ~(size_t)255;
        return p;
    };
    f16* WT  = (f16*)alloc(3ULL * 1024 * 1024 * 2);   // WqT|WkT|WvT contiguous
    f16* WoT = (f16*)alloc(1024ULL * 1024 * 2);
    f16* qb  = (f16*)alloc(8192ULL * 1024 * 2);   // head-major [(b,h)][s][64]
    f16* kb2 = (f16*)alloc(8192ULL * 1024 * 2);   // [bh][tile] lane-major perm K
    f16* vb2 = (f16*)alloc(8192ULL * 1024 * 2);   // [bh][tile] lane-major V^T
    f16* cat = (f16*)alloc(8192ULL * 1024 * 2);   // [B*S][H*VS]

    k_transpose_all<<<1024, 256, 0, stream>>>(Wq, Wk, Wv, Wo, WT, WoT);

    const float SC = 0.125f * 1.44269504089f;   // 1/sqrt(64) * log2(e), folded into q
    k_gemm_qkv256<<<dim3(32, 24), 512, 0, stream>>>(Q, K, V, WT, bq, bk, bv,
                                                    qb, kb2, vb2, SC);

    k_attn<<<512, 512, 0, stream>>>(qb, kb2, vb2, cat);

    k_gemm_out256<<<dim3(32, 8), 512, 0, stream>>>(cat, WoT, bo, (float*)d_out);
}